// Round 2
// baseline (206.784 us; speedup 1.0000x reference)
//
#include <hip/hip_runtime.h>

// CenterLoss: out = mean_i sqrt( sum_d (x[i,d] - weight[targets[i],d])^2 + EPS )
// x: [N=65536, D=512] f32, weight: [C=1000, D=512] f32, targets: [N] i32.
// Memory-bound: 128 MiB x-stream dominates; weight (2 MB) lives in L2/L3.

constexpr int D = 512;
constexpr float EPS = 1e-6f;

__global__ __launch_bounds__(256) void centerloss_kernel(
    const float* __restrict__ x,
    const float* __restrict__ w,
    const int*   __restrict__ targets,
    float* __restrict__ out,
    int n_rows)
{
    const int lane = threadIdx.x & 63;
    const int wave = threadIdx.x >> 6;            // 0..3
    const int wavesPerBlock = blockDim.x >> 6;    // 4
    const int globalWave = blockIdx.x * wavesPerBlock + wave;
    const int waveCount = gridDim.x * wavesPerBlock;

    float wsum = 0.0f;  // running sum of distances for this wave's rows

    for (int row = globalWave; row < n_rows; row += waveCount) {
        const int t = targets[row];               // wave-uniform broadcast load
        const float4* __restrict__ xr =
            reinterpret_cast<const float4*>(x + (size_t)row * D);
        const float4* __restrict__ wr =
            reinterpret_cast<const float4*>(w + (size_t)t * D);

        // 512 floats = 128 float4; 64 lanes -> 2 float4 per lane, coalesced 1 KiB/instr
        float4 xa = xr[lane];
        float4 wa = wr[lane];
        float4 xb = xr[lane + 64];
        float4 wb = wr[lane + 64];

        float acc = 0.0f, d0;
        d0 = xa.x - wa.x; acc = fmaf(d0, d0, acc);
        d0 = xa.y - wa.y; acc = fmaf(d0, d0, acc);
        d0 = xa.z - wa.z; acc = fmaf(d0, d0, acc);
        d0 = xa.w - wa.w; acc = fmaf(d0, d0, acc);
        d0 = xb.x - wb.x; acc = fmaf(d0, d0, acc);
        d0 = xb.y - wb.y; acc = fmaf(d0, d0, acc);
        d0 = xb.z - wb.z; acc = fmaf(d0, d0, acc);
        d0 = xb.w - wb.w; acc = fmaf(d0, d0, acc);

        // butterfly reduce across the 64-lane wave (all lanes end with the sum)
        #pragma unroll
        for (int off = 1; off < 64; off <<= 1)
            acc += __shfl_xor(acc, off, 64);

        wsum += sqrtf(acc + EPS);
    }

    // wsum is identical across lanes of a wave (post-butterfly); take lane 0.
    __shared__ float smem[8];
    if (lane == 0) smem[wave] = wsum;
    __syncthreads();

    if (threadIdx.x == 0) {
        float s = 0.0f;
        for (int i = 0; i < wavesPerBlock; ++i) s += smem[i];
        atomicAdd(out, s * (1.0f / (float)n_rows));   // pre-scaled: out = mean
    }
}

extern "C" void kernel_launch(void* const* d_in, const int* in_sizes, int n_in,
                              void* d_out, int out_size, void* d_ws, size_t ws_size,
                              hipStream_t stream) {
    const float* x       = (const float*)d_in[0];
    const float* weight  = (const float*)d_in[1];
    const int*   targets = (const int*)d_in[2];
    float* out = (float*)d_out;

    const int n_rows = in_sizes[2];   // 65536

    // d_out is poisoned to 0xAA before every call; zero it for the atomicAdd.
    hipMemsetAsync(d_out, 0, sizeof(float), stream);

    // 2048 blocks x 4 waves = 8192 waves -> 8 rows per wave, grid-stride.
    const int block = 256;
    const int grid  = 2048;
    centerloss_kernel<<<grid, block, 0, stream>>>(x, weight, targets, out, n_rows);
}

// Round 3
// 199.949 us; speedup vs baseline: 1.0342x; 1.0342x over previous
//
#include <hip/hip_runtime.h>

// CenterLoss: out = mean_i sqrt( sum_d (x[i,d] - weight[targets[i],d])^2 + EPS )
// x: [N=65536, D=512] f32, weight: [C=1000, D=512] f32, targets: [N] i32.
// HBM-bound: 128 MiB x-stream dominates; weight (2 MB) is L2/L3-resident.
//
// R3 change vs R2: contiguous 8-row span per wave + one-shot target prefetch
// (lane k holds targets[base+k], broadcast via __shfl). Removes the per-row
// t->load serialization so x/w loads issue with no memory-dependent prologue.

constexpr int D = 512;
constexpr float EPS = 1e-6f;

__global__ __launch_bounds__(256) void centerloss_kernel(
    const float* __restrict__ x,
    const float* __restrict__ w,
    const int*   __restrict__ targets,
    float* __restrict__ out,
    int n_rows)
{
    const int lane = threadIdx.x & 63;
    const int wave = threadIdx.x >> 6;              // 0..3
    const int wavesPerBlock = blockDim.x >> 6;      // 4
    const int gw = blockIdx.x * wavesPerBlock + wave;
    const int waveCount = gridDim.x * wavesPerBlock;        // 8192
    const int rpw = (n_rows + waveCount - 1) / waveCount;   // 8
    const int base = gw * rpw;

    // Prefetch this wave's targets in ONE load: lane k holds targets[base+k].
    int tml = 0;
    if (lane < rpw && base + lane < n_rows) tml = targets[base + lane];

    float wsum = 0.0f;  // running sum of distances for this wave's rows

    for (int k = 0; k < rpw; ++k) {
        const int row = base + k;
        if (row >= n_rows) break;
        const int t = __shfl(tml, k, 64);           // register broadcast, no mem dep

        const float4* __restrict__ xr =
            reinterpret_cast<const float4*>(x + (size_t)row * D);
        const float4* __restrict__ wr =
            reinterpret_cast<const float4*>(w + (size_t)t * D);

        // 512 floats = 128 float4; 64 lanes -> 2 float4/lane, 1 KiB per wave-instr
        float4 xa = xr[lane];
        float4 xb = xr[lane + 64];
        float4 wa = wr[lane];
        float4 wb = wr[lane + 64];

        float acc = 0.0f, d0;
        d0 = xa.x - wa.x; acc = fmaf(d0, d0, acc);
        d0 = xa.y - wa.y; acc = fmaf(d0, d0, acc);
        d0 = xa.z - wa.z; acc = fmaf(d0, d0, acc);
        d0 = xa.w - wa.w; acc = fmaf(d0, d0, acc);
        d0 = xb.x - wb.x; acc = fmaf(d0, d0, acc);
        d0 = xb.y - wb.y; acc = fmaf(d0, d0, acc);
        d0 = xb.z - wb.z; acc = fmaf(d0, d0, acc);
        d0 = xb.w - wb.w; acc = fmaf(d0, d0, acc);

        // butterfly reduce across the 64-lane wave (all lanes end with the sum)
        #pragma unroll
        for (int off = 1; off < 64; off <<= 1)
            acc += __shfl_xor(acc, off, 64);

        wsum += sqrtf(acc + EPS);
    }

    // wsum is identical across lanes of a wave (post-butterfly); take lane 0.
    __shared__ float smem[8];
    if (lane == 0) smem[wave] = wsum;
    __syncthreads();

    if (threadIdx.x == 0) {
        float s = 0.0f;
        for (int i = 0; i < wavesPerBlock; ++i) s += smem[i];
        atomicAdd(out, s * (1.0f / (float)n_rows));   // pre-scaled: out = mean
    }
}

extern "C" void kernel_launch(void* const* d_in, const int* in_sizes, int n_in,
                              void* d_out, int out_size, void* d_ws, size_t ws_size,
                              hipStream_t stream) {
    const float* x       = (const float*)d_in[0];
    const float* weight  = (const float*)d_in[1];
    const int*   targets = (const int*)d_in[2];
    float* out = (float*)d_out;

    const int n_rows = in_sizes[2];   // 65536

    // d_out is poisoned to 0xAA before every call; zero it for the atomicAdd.
    hipMemsetAsync(d_out, 0, sizeof(float), stream);

    // 2048 blocks x 4 waves = 8192 waves -> 8 contiguous rows per wave.
    const int block = 256;
    const int grid  = 2048;
    centerloss_kernel<<<grid, block, 0, stream>>>(x, weight, targets, out, n_rows);
}